// Round 1
// baseline (3849.950 us; speedup 1.0000x reference)
//
#include <hip/hip_runtime.h>

#define NPTS   65536
#define NBATCH 8
#define TSIZE  131072
#define TM1    (TSIZE - 1)

__device__ __forceinline__ unsigned hashf(int code) {
    unsigned u = (unsigned)code * 2654435761u;
    return (u >> 13) & TM1;
}

// ---------- init origin bits to +inf ----------
__global__ void init_origin(int* ob) {
    if (threadIdx.x < 3) ob[threadIdx.x] = 0x7F800000; // +inf
}

// ---------- global per-component min of xyz ----------
__global__ void minred(const float* __restrict__ xyz, int* __restrict__ ob) {
    int tid = threadIdx.x;
    float mx = INFINITY, my = INFINITY, mz = INFINITY;
    size_t total = (size_t)NBATCH * NPTS;
    for (size_t i = (size_t)blockIdx.x * blockDim.x + tid; i < total;
         i += (size_t)gridDim.x * blockDim.x) {
        mx = fminf(mx, xyz[i * 3 + 0]);
        my = fminf(my, xyz[i * 3 + 1]);
        mz = fminf(mz, xyz[i * 3 + 2]);
    }
    __shared__ float sx[256], sy[256], sz[256];
    sx[tid] = mx; sy[tid] = my; sz[tid] = mz;
    __syncthreads();
    for (int s = 128; s > 0; s >>= 1) {
        if (tid < s) {
            sx[tid] = fminf(sx[tid], sx[tid + s]);
            sy[tid] = fminf(sy[tid], sy[tid + s]);
            sz[tid] = fminf(sz[tid], sz[tid + s]);
        }
        __syncthreads();
    }
    if (tid == 0) {
        // coords are >= 0, so signed-int compare of float bits preserves order
        atomicMin(&ob[0], __float_as_int(sx[0]));
        atomicMin(&ob[1], __float_as_int(sy[0]));
        atomicMin(&ob[2], __float_as_int(sz[0]));
    }
}

// ---------- compute voxel codes per point + hash insert ----------
__global__ void build_codes(const float* __restrict__ xyz, const int* __restrict__ ob,
                            int* __restrict__ pcode, int* __restrict__ hashk) {
    int b = blockIdx.y;
    int p = blockIdx.x * blockDim.x + threadIdx.x;
    size_t gi = (size_t)b * NPTS + p;
    float ox = __int_as_float(ob[0]);
    float oy = __int_as_float(ob[1]);
    float oz = __int_as_float(ob[2]);
    float x = xyz[gi * 3 + 0], y = xyz[gi * 3 + 1], z = xyz[gi * 3 + 2];
    int vx = (int)((x - ox) / 0.4f); if (vx < 0) vx = 0;
    int vy = (int)((y - oy) / 0.4f); if (vy < 0) vy = 0;
    int vz = (int)((z - oz) / 0.4f); if (vz < 0) vz = 0;
    int code = vx + 1000 * (vy + 1000 * vz);
    pcode[gi] = code;
    int* hk = hashk + (size_t)b * TSIZE;
    unsigned s = hashf(code);
    while (true) {
        int prev = atomicCAS(&hk[s], -1, code);
        if (prev == -1 || prev == code) break;
        s = (s + 1) & TM1;
    }
}

// ---------- assign voxel ids to occupied hash slots ----------
__global__ void assign_ids(const int* __restrict__ hashk, int* __restrict__ hashv,
                           int* __restrict__ nvox, int* __restrict__ voxcode) {
    int b = blockIdx.y;
    int s = blockIdx.x * blockDim.x + threadIdx.x;
    int k = hashk[(size_t)b * TSIZE + s];
    if (k != -1) {
        int id = atomicAdd(&nvox[b], 1);
        hashv[(size_t)b * TSIZE + s] = id;
        voxcode[(size_t)b * NPTS + id] = k;
    }
}

// ---------- per-point: record inv, accumulate masked feature sums ----------
__global__ void point_pass(const int* __restrict__ pcode, const int* __restrict__ hashk,
                           const int* __restrict__ hashv, const float* __restrict__ feat,
                           const float* __restrict__ mask, int* __restrict__ inv,
                           float* __restrict__ cnt, float* __restrict__ fsum) {
    int b = blockIdx.y;
    int p = blockIdx.x * blockDim.x + threadIdx.x;
    size_t gi = (size_t)b * NPTS + p;
    int code = pcode[gi];
    const int* hk = hashk + (size_t)b * TSIZE;
    unsigned s = hashf(code);
    while (hk[s] != code) s = (s + 1) & TM1;
    int v = hashv[(size_t)b * TSIZE + s];
    inv[gi] = v;
    float m = mask[gi];
    atomicAdd(&cnt[(size_t)b * NPTS + v], m);
    const float* f = feat + gi * 16;
    float* fs = fsum + ((size_t)b * NPTS + v) * 16;
    #pragma unroll
    for (int c = 0; c < 16; c++) atomicAdd(&fs[c], f[c] * m);
}

// ---------- vfeat = fsum / max(cnt,1) ----------
__global__ void vfeat_div(float* __restrict__ fsum, const float* __restrict__ cnt,
                          const int* __restrict__ nvox) {
    int b = blockIdx.y;
    int i = blockIdx.x * blockDim.x + threadIdx.x; // over NPTS*16
    int v = i >> 4;
    if (v >= nvox[b]) return;
    float cn = fmaxf(cnt[(size_t)b * NPTS + v], 1.0f);
    fsum[(size_t)b * NPTS * 16 + i] /= cn;
}

// ---------- submanifold conv: one 64-thread block per valid voxel ----------
template <int Cin, int Cout>
__global__ __launch_bounds__(64) void conv_k(
    const float* __restrict__ in, float* __restrict__ outp,
    const float* __restrict__ W, const float* __restrict__ bias,
    const int* __restrict__ hashk, const int* __restrict__ hashv,
    const int* __restrict__ voxcode, const int* __restrict__ nvox) {
    constexpr int J = (Cout + 63) / 64;
    int b = blockIdx.y;
    int v = blockIdx.x;
    if (v >= nvox[b]) return;
    __shared__ int snbr[27];
    __shared__ float srow[Cin];
    int tid = threadIdx.x;
    int code = voxcode[(size_t)b * NPTS + v];
    if (tid < 27) {
        int ko = tid;
        int nb = -1;
        if (ko == 13) {
            nb = v;
        } else {
            int dz = ko / 9 - 1, dy = (ko / 3) % 3 - 1, dx = ko % 3 - 1;
            int x = code % 1000, y = (code / 1000) % 1000, z = code / 1000000;
            int nx = x + dx, ny = y + dy, nz = z + dz;
            if (nx >= 0 && nx < 1000 && ny >= 0 && ny < 1000 && nz >= 0 && nz < 1000) {
                int ncode = code + dx + 1000 * dy + 1000000 * dz;
                const int* hk = hashk + (size_t)b * TSIZE;
                unsigned s = hashf(ncode);
                while (true) {
                    int k = hk[s];
                    if (k == ncode) { nb = hashv[(size_t)b * TSIZE + s]; break; }
                    if (k == -1) break;
                    s = (s + 1) & TM1;
                }
            }
        }
        snbr[ko] = nb;
    }
    __syncthreads();
    float acc[J];
    #pragma unroll
    for (int j = 0; j < J; j++) acc[j] = 0.0f;
    for (int ko = 0; ko < 27; ko++) {
        int nb = snbr[ko];        // uniform across block
        if (nb < 0) continue;
        if (tid < Cin) srow[tid] = in[((size_t)b * NPTS + nb) * Cin + tid];
        __syncthreads();
        const float* Wk = W + ko * Cin * Cout;
        #pragma unroll
        for (int ci = 0; ci < Cin; ci++) {
            float a = srow[ci];
            #pragma unroll
            for (int j = 0; j < J; j++) {
                int co = tid + 64 * j;
                if (Cout >= 64 || co < Cout) acc[j] += a * Wk[ci * Cout + co];
            }
        }
        __syncthreads();
    }
    #pragma unroll
    for (int j = 0; j < J; j++) {
        int co = tid + 64 * j;
        if (Cout >= 64 || co < Cout)
            outp[((size_t)b * NPTS + v) * Cout + co] = acc[j] + bias[co];
    }
}

// ---------- BN stats: per-channel sum and sumsq over valid voxels ----------
template <int C>
__global__ void bn_stats(const float* __restrict__ h, const int* __restrict__ nvox,
                         float* __restrict__ sums) {
    constexpr int RPB = 256 / C;
    int b = blockIdx.y;
    int nv = nvox[b];
    int tid = threadIdx.x;
    int c = tid % C;
    int r = tid / C;
    float s0 = 0.0f, s1 = 0.0f;
    for (int v = blockIdx.x * RPB + r; v < nv; v += gridDim.x * RPB) {
        float x = h[((size_t)b * NPTS + v) * C + c];
        s0 += x;
        s1 += x * x;
    }
    __shared__ float l0[256], l1[256];
    l0[tid] = s0; l1[tid] = s1;
    __syncthreads();
    for (int s = 128; s >= C; s >>= 1) {
        if (tid < s) { l0[tid] += l0[tid + s]; l1[tid] += l1[tid + s]; }
        __syncthreads();
    }
    if (tid < C) {
        atomicAdd(&sums[c], l0[tid]);
        atomicAdd(&sums[C + c], l1[tid]);
    }
}

template <int C>
__global__ void bn_finalize(const float* __restrict__ sums, const int* __restrict__ nvox,
                            const float* __restrict__ g, const float* __restrict__ be,
                            float* __restrict__ scale, float* __restrict__ shift) {
    int c = threadIdx.x;
    if (c >= C) return;
    float n = 0.0f;
    for (int b = 0; b < NBATCH; b++) n += (float)nvox[b];
    n = fmaxf(n, 1.0f);
    float mean = sums[c] / n;
    float var = sums[C + c] / n - mean * mean;
    float a = g[c] * rsqrtf(var + 1e-5f);
    scale[c] = a;
    shift[c] = be[c] - mean * a;
}

template <int C>
__global__ void bn_apply(float* __restrict__ h, const int* __restrict__ nvox,
                         const float* __restrict__ sc, const float* __restrict__ sh) {
    int b = blockIdx.y;
    size_t i = (size_t)blockIdx.x * blockDim.x + threadIdx.x; // over NPTS*C
    int v = (int)(i / C);
    if (v >= nvox[b]) return;
    int c = (int)(i % C);
    size_t idx = (size_t)b * NPTS * C + i;
    float x = h[idx] * sc[c] + sh[c];
    h[idx] = fmaxf(x, 0.0f);
}

// ---------- fused BN3 + ReLU + gather to points + mask ----------
__global__ void out_gather(const float* __restrict__ h3, const int* __restrict__ inv,
                           const float* __restrict__ mask, const float* __restrict__ sc,
                           const float* __restrict__ sh, float* __restrict__ out) {
    int b = blockIdx.y;
    size_t i = (size_t)blockIdx.x * blockDim.x + threadIdx.x; // over NPTS*128
    int p = (int)(i >> 7);
    int c = (int)(i & 127);
    size_t gi = (size_t)b * NPTS + p;
    int v = inv[gi];
    float m = mask[gi];
    float x = h3[((size_t)b * NPTS + v) * 128 + c];
    x = fmaxf(x * sc[c] + sh[c], 0.0f);
    out[gi * 128 + c] = x * m;
}

extern "C" void kernel_launch(void* const* d_in, const int* in_sizes, int n_in,
                              void* d_out, int out_size, void* d_ws, size_t ws_size,
                              hipStream_t stream) {
    const float* xyz  = (const float*)d_in[0];
    const float* feat = (const float*)d_in[1];
    const float* mask = (const float*)d_in[2];
    const float* W1 = (const float*)d_in[3];
    const float* b1 = (const float*)d_in[4];
    const float* g1 = (const float*)d_in[5];
    const float* be1 = (const float*)d_in[6];
    const float* W2 = (const float*)d_in[7];
    const float* b2 = (const float*)d_in[8];
    const float* g2 = (const float*)d_in[9];
    const float* be2 = (const float*)d_in[10];
    const float* W3 = (const float*)d_in[11];
    const float* b3 = (const float*)d_in[12];
    const float* g3 = (const float*)d_in[13];
    const float* be3 = (const float*)d_in[14];
    float* out = (float*)d_out;

    char* ws = (char*)d_ws;
    size_t off = 0;
    auto alloc = [&](size_t bytes) {
        void* p = ws + off;
        off += (bytes + 255) & ~(size_t)255;
        return p;
    };
    int*   hashk   = (int*)alloc((size_t)NBATCH * TSIZE * 4);
    int*   hashv   = (int*)alloc((size_t)NBATCH * TSIZE * 4);
    int*   nvox    = (int*)alloc(NBATCH * 4);
    int*   origin  = (int*)alloc(16);
    int*   pcode   = (int*)alloc((size_t)NBATCH * NPTS * 4);
    int*   voxcode = (int*)alloc((size_t)NBATCH * NPTS * 4);
    int*   inv     = (int*)alloc((size_t)NBATCH * NPTS * 4);
    float* cnt     = (float*)alloc((size_t)NBATCH * NPTS * 4);
    float* bnsums  = (float*)alloc(256 * 4);
    float* bnscale = (float*)alloc(128 * 4);
    float* bnshift = (float*)alloc(128 * 4);
    float* A       = (float*)alloc((size_t)NBATCH * NPTS * 64 * 4);  // vfeat(16) then h2(64)
    float* Bb      = (float*)alloc((size_t)NBATCH * NPTS * 128 * 4); // h1(32) then h3(128)

    // ---- zero / sentinel inits (ws is poisoned) ----
    hipMemsetAsync(hashk, 0xFF, (size_t)NBATCH * TSIZE * 4, stream); // keys = -1
    hipMemsetAsync(nvox, 0, NBATCH * 4, stream);
    hipMemsetAsync(cnt, 0, (size_t)NBATCH * NPTS * 4, stream);
    hipMemsetAsync(A, 0, (size_t)NBATCH * NPTS * 16 * 4, stream);    // fsum region
    init_origin<<<1, 64, 0, stream>>>(origin);

    // ---- voxelization ----
    minred<<<512, 256, 0, stream>>>(xyz, origin);
    build_codes<<<dim3(NPTS / 256, NBATCH), 256, 0, stream>>>(xyz, origin, pcode, hashk);
    assign_ids<<<dim3(TSIZE / 256, NBATCH), 256, 0, stream>>>(hashk, hashv, nvox, voxcode);
    point_pass<<<dim3(NPTS / 256, NBATCH), 256, 0, stream>>>(pcode, hashk, hashv, feat, mask,
                                                             inv, cnt, A);
    vfeat_div<<<dim3(NPTS * 16 / 256, NBATCH), 256, 0, stream>>>(A, cnt, nvox);

    // ---- layer 1: 16 -> 32 ----
    conv_k<16, 32><<<dim3(NPTS, NBATCH), 64, 0, stream>>>(A, Bb, W1, b1, hashk, hashv, voxcode, nvox);
    hipMemsetAsync(bnsums, 0, 256 * 4, stream);
    bn_stats<32><<<dim3(64, NBATCH), 256, 0, stream>>>(Bb, nvox, bnsums);
    bn_finalize<32><<<1, 128, 0, stream>>>(bnsums, nvox, g1, be1, bnscale, bnshift);
    bn_apply<32><<<dim3(NPTS * 32 / 256, NBATCH), 256, 0, stream>>>(Bb, nvox, bnscale, bnshift);

    // ---- layer 2: 32 -> 64 ----
    conv_k<32, 64><<<dim3(NPTS, NBATCH), 64, 0, stream>>>(Bb, A, W2, b2, hashk, hashv, voxcode, nvox);
    hipMemsetAsync(bnsums, 0, 256 * 4, stream);
    bn_stats<64><<<dim3(64, NBATCH), 256, 0, stream>>>(A, nvox, bnsums);
    bn_finalize<64><<<1, 128, 0, stream>>>(bnsums, nvox, g2, be2, bnscale, bnshift);
    bn_apply<64><<<dim3(NPTS * 64 / 256, NBATCH), 256, 0, stream>>>(A, nvox, bnscale, bnshift);

    // ---- layer 3: 64 -> 128 ----
    conv_k<64, 128><<<dim3(NPTS, NBATCH), 64, 0, stream>>>(A, Bb, W3, b3, hashk, hashv, voxcode, nvox);
    hipMemsetAsync(bnsums, 0, 256 * 4, stream);
    bn_stats<128><<<dim3(64, NBATCH), 256, 0, stream>>>(Bb, nvox, bnsums);
    bn_finalize<128><<<1, 128, 0, stream>>>(bnsums, nvox, g3, be3, bnscale, bnshift);

    // ---- fused BN3 + ReLU + gather + mask ----
    out_gather<<<dim3(NPTS * 128 / 256, NBATCH), 256, 0, stream>>>(Bb, inv, mask, bnscale,
                                                                   bnshift, out);
}

// Round 2
// 3708.749 us; speedup vs baseline: 1.0381x; 1.0381x over previous
//
#include <hip/hip_runtime.h>

#define NPTS   65536
#define NBATCH 8
#define TSIZE  131072
#define TM1    (TSIZE - 1)
#define CAP    8192     // pairs per (b,ko) bucket
#define PPB    64       // pairs per conv_off block

__device__ __forceinline__ unsigned hashf(int code) {
    unsigned u = (unsigned)code * 2654435761u;
    return (u >> 13) & TM1;
}

// ---------- init origin bits to +inf ----------
__global__ void init_origin(int* ob) {
    if (threadIdx.x < 3) ob[threadIdx.x] = 0x7F800000; // +inf
}

// ---------- global per-component min of xyz ----------
__global__ void minred(const float* __restrict__ xyz, int* __restrict__ ob) {
    int tid = threadIdx.x;
    float mx = INFINITY, my = INFINITY, mz = INFINITY;
    size_t total = (size_t)NBATCH * NPTS;
    for (size_t i = (size_t)blockIdx.x * blockDim.x + tid; i < total;
         i += (size_t)gridDim.x * blockDim.x) {
        mx = fminf(mx, xyz[i * 3 + 0]);
        my = fminf(my, xyz[i * 3 + 1]);
        mz = fminf(mz, xyz[i * 3 + 2]);
    }
    __shared__ float sx[256], sy[256], sz[256];
    sx[tid] = mx; sy[tid] = my; sz[tid] = mz;
    __syncthreads();
    for (int s = 128; s > 0; s >>= 1) {
        if (tid < s) {
            sx[tid] = fminf(sx[tid], sx[tid + s]);
            sy[tid] = fminf(sy[tid], sy[tid + s]);
            sz[tid] = fminf(sz[tid], sz[tid + s]);
        }
        __syncthreads();
    }
    if (tid == 0) {
        // coords >= 0 so signed-int compare of float bits preserves order
        atomicMin(&ob[0], __float_as_int(sx[0]));
        atomicMin(&ob[1], __float_as_int(sy[0]));
        atomicMin(&ob[2], __float_as_int(sz[0]));
    }
}

// ---------- voxel codes per point + hash insert ----------
__global__ void build_codes(const float* __restrict__ xyz, const int* __restrict__ ob,
                            int* __restrict__ pcode, int* __restrict__ hashk) {
    int b = blockIdx.y;
    int p = blockIdx.x * blockDim.x + threadIdx.x;
    size_t gi = (size_t)b * NPTS + p;
    float ox = __int_as_float(ob[0]);
    float oy = __int_as_float(ob[1]);
    float oz = __int_as_float(ob[2]);
    float x = xyz[gi * 3 + 0], y = xyz[gi * 3 + 1], z = xyz[gi * 3 + 2];
    int vx = (int)((x - ox) / 0.4f); if (vx < 0) vx = 0;
    int vy = (int)((y - oy) / 0.4f); if (vy < 0) vy = 0;
    int vz = (int)((z - oz) / 0.4f); if (vz < 0) vz = 0;
    int code = vx + 1000 * (vy + 1000 * vz);
    pcode[gi] = code;
    int* hk = hashk + (size_t)b * TSIZE;
    unsigned s = hashf(code);
    while (true) {
        int prev = atomicCAS(&hk[s], -1, code);
        if (prev == -1 || prev == code) break;
        s = (s + 1) & TM1;
    }
}

// ---------- assign voxel ids to occupied hash slots ----------
__global__ void assign_ids(const int* __restrict__ hashk, int* __restrict__ hashv,
                           int* __restrict__ nvox, int* __restrict__ voxcode) {
    int b = blockIdx.y;
    int s = blockIdx.x * blockDim.x + threadIdx.x;
    int k = hashk[(size_t)b * TSIZE + s];
    if (k != -1) {
        int id = atomicAdd(&nvox[b], 1);
        hashv[(size_t)b * TSIZE + s] = id;
        voxcode[(size_t)b * NPTS + id] = k;
    }
}

// ---------- per-point: record inv, accumulate masked feature sums ----------
__global__ void point_pass(const int* __restrict__ pcode, const int* __restrict__ hashk,
                           const int* __restrict__ hashv, const float* __restrict__ feat,
                           const float* __restrict__ mask, int* __restrict__ inv,
                           float* __restrict__ cnt, float* __restrict__ fsum) {
    int b = blockIdx.y;
    int p = blockIdx.x * blockDim.x + threadIdx.x;
    size_t gi = (size_t)b * NPTS + p;
    int code = pcode[gi];
    const int* hk = hashk + (size_t)b * TSIZE;
    unsigned s = hashf(code);
    while (hk[s] != code) s = (s + 1) & TM1;
    int v = hashv[(size_t)b * TSIZE + s];
    inv[gi] = v;
    float m = mask[gi];
    atomicAdd(&cnt[(size_t)b * NPTS + v], m);
    const float* f = feat + gi * 16;
    float* fs = fsum + ((size_t)b * NPTS + v) * 16;
    #pragma unroll
    for (int c = 0; c < 16; c++) atomicAdd(&fs[c], f[c] * m);
}

// ---------- vfeat = fsum / max(cnt,1) ----------
__global__ void vfeat_div(float* __restrict__ fsum, const float* __restrict__ cnt,
                          const int* __restrict__ nvox) {
    int b = blockIdx.y;
    int i = blockIdx.x * blockDim.x + threadIdx.x; // over NPTS*16
    int v = i >> 4;
    if (v >= nvox[b]) return;
    float cn = fmaxf(cnt[(size_t)b * NPTS + v], 1.0f);
    fsum[(size_t)b * NPTS * 16 + i] /= cn;
}

// ---------- build off-center rulebook: per (b,ko) pair lists (v_out<<16 | v_in) ----------
__global__ void build_pairs(const int* __restrict__ hashk, const int* __restrict__ hashv,
                            const int* __restrict__ voxcode, const int* __restrict__ nvox,
                            unsigned* __restrict__ pairs, int* __restrict__ paircnt) {
    int b = blockIdx.y;
    int v = blockIdx.x * 4 + (threadIdx.x >> 6);
    int ko = threadIdx.x & 63;
    if (v >= nvox[b]) return;
    if (ko >= 27 || ko == 13) return;
    int code = voxcode[(size_t)b * NPTS + v];
    int dz = ko / 9 - 1, dy = (ko / 3) % 3 - 1, dx = ko % 3 - 1;
    int x = code % 1000, y = (code / 1000) % 1000, z = code / 1000000;
    int nx = x + dx, ny = y + dy, nz = z + dz;
    if (nx < 0 || nx >= 1000 || ny < 0 || ny >= 1000 || nz < 0 || nz >= 1000) return;
    int ncode = code + dx + 1000 * dy + 1000000 * dz;
    const int* hk = hashk + (size_t)b * TSIZE;
    unsigned s = hashf(ncode);
    int nb = -1;
    while (true) {
        int k = hk[s];
        if (k == ncode) { nb = hashv[(size_t)b * TSIZE + s]; break; }
        if (k == -1) break;
        s = (s + 1) & TM1;
    }
    if (nb >= 0) {
        int bucket = b * 27 + ko;
        int slot = atomicAdd(&paircnt[bucket], 1);
        if (slot < CAP)
            pairs[(size_t)bucket * CAP + slot] = ((unsigned)v << 16) | (unsigned)nb;
    }
}

// ---------- dense center GEMM: out = xform(in) @ W13 + bias over valid rows ----------
// tile: 64 rows x Cout cols, 256 threads, W13 + A-tile in LDS
template <int Cin, int Cout, bool XFORM>
__global__ __launch_bounds__(256) void conv_center(
    const float* __restrict__ in, float* __restrict__ outp,
    const float* __restrict__ W13, const float* __restrict__ bias,
    const float* __restrict__ sc, const float* __restrict__ sh,
    const int* __restrict__ nvox) {
    constexpr int BR  = 64;
    constexpr int CT  = (Cout < 64) ? Cout : 64;   // col threads
    constexpr int RG  = 256 / CT;                  // row groups
    constexpr int RPT = BR / RG;                   // rows per thread
    constexpr int J   = Cout / CT;                 // cols per thread
    int b = blockIdx.y;
    int nv = nvox[b];
    int v0 = blockIdx.x * BR;
    if (v0 >= nv) return;
    __shared__ __align__(16) float A_s[Cin][BR + 4];
    __shared__ __align__(16) float W_s[Cin * Cout];
    int t = threadIdx.x;
    // stage W13
    for (int i4 = t; i4 < Cin * Cout / 4; i4 += 256)
        ((float4*)W_s)[i4] = ((const float4*)W13)[i4];
    // stage A tile (float4 global loads; rows beyond nv load garbage, never stored)
    const float* inb = in + (size_t)b * NPTS * Cin;
    for (int i4 = t; i4 < BR * Cin / 4; i4 += 256) {
        int lin = i4 * 4;
        int r = lin / Cin, ci = lin % Cin;
        float4 val = *(const float4*)&inb[(size_t)(v0 + r) * Cin + ci];
        if (XFORM) {
            val.x = fmaxf(val.x * sc[ci + 0] + sh[ci + 0], 0.0f);
            val.y = fmaxf(val.y * sc[ci + 1] + sh[ci + 1], 0.0f);
            val.z = fmaxf(val.z * sc[ci + 2] + sh[ci + 2], 0.0f);
            val.w = fmaxf(val.w * sc[ci + 3] + sh[ci + 3], 0.0f);
        }
        A_s[ci + 0][r] = val.x;
        A_s[ci + 1][r] = val.y;
        A_s[ci + 2][r] = val.z;
        A_s[ci + 3][r] = val.w;
    }
    __syncthreads();
    int c = t % CT;
    int r0 = (t / CT) * RPT;
    float acc[RPT][J];
    #pragma unroll
    for (int r = 0; r < RPT; r++)
        #pragma unroll
        for (int j = 0; j < J; j++) acc[r][j] = 0.0f;
    #pragma unroll 4
    for (int ci = 0; ci < Cin; ci++) {
        float4 a4[RPT / 4];
        #pragma unroll
        for (int k = 0; k < RPT / 4; k++)
            a4[k] = *(const float4*)&A_s[ci][r0 + 4 * k];
        float w[J];
        #pragma unroll
        for (int j = 0; j < J; j++) w[j] = W_s[ci * Cout + c + CT * j];
        #pragma unroll
        for (int k = 0; k < RPT / 4; k++) {
            #pragma unroll
            for (int j = 0; j < J; j++) {
                acc[4 * k + 0][j] += a4[k].x * w[j];
                acc[4 * k + 1][j] += a4[k].y * w[j];
                acc[4 * k + 2][j] += a4[k].z * w[j];
                acc[4 * k + 3][j] += a4[k].w * w[j];
            }
        }
    }
    float* ob = outp + (size_t)b * NPTS * Cout;
    #pragma unroll
    for (int r = 0; r < RPT; r++) {
        int row = v0 + r0 + r;
        if (row < nv) {
            #pragma unroll
            for (int j = 0; j < J; j++)
                ob[(size_t)row * Cout + c + CT * j] = acc[r][j] + bias[c + CT * j];
        }
    }
}

// ---------- off-center: gather 64 pair-rows, GEMM with W[ko] in LDS, scatter-add ----------
template <int Cin, int Cout, bool XFORM>
__global__ __launch_bounds__(256) void conv_off(
    const float* __restrict__ in, float* __restrict__ outp,
    const float* __restrict__ W, const float* __restrict__ sc,
    const float* __restrict__ sh, const unsigned* __restrict__ pairs,
    const int* __restrict__ paircnt) {
    constexpr int BR  = PPB;
    constexpr int CT  = (Cout < 64) ? Cout : 64;
    constexpr int RG  = 256 / CT;
    constexpr int RPT = BR / RG;
    constexpr int J   = Cout / CT;
    int bk = blockIdx.y;            // b*27 + ko
    int ko = bk % 27;
    int b  = bk / 27;
    int cnt = paircnt[bk];
    if (cnt > CAP) cnt = CAP;
    int start = blockIdx.x * BR;
    if (start >= cnt) return;       // ko==13 buckets have cnt==0 -> exit
    int nActive = cnt - start; if (nActive > BR) nActive = BR;
    __shared__ __align__(16) float A_s[Cin][BR + 4];
    __shared__ __align__(16) float W_s[Cin * Cout];
    __shared__ unsigned pr_s[BR];
    int t = threadIdx.x;
    const float* Wk = W + (size_t)ko * Cin * Cout;
    for (int i4 = t; i4 < Cin * Cout / 4; i4 += 256)
        ((float4*)W_s)[i4] = ((const float4*)Wk)[i4];
    const unsigned* pb = pairs + (size_t)bk * CAP + start;
    if (t < BR) pr_s[t] = pb[t];
    __syncthreads();
    // gather pair input rows (garbage rows beyond nActive are computed but not scattered)
    const float* inb = in + (size_t)b * NPTS * Cin;
    for (int i4 = t; i4 < BR * Cin / 4; i4 += 256) {
        int lin = i4 * 4;
        int r = lin / Cin, ci = lin % Cin;
        int vin = (int)(pr_s[r] & 0xffffu);
        float4 val = *(const float4*)&inb[(size_t)vin * Cin + ci];
        if (XFORM) {
            val.x = fmaxf(val.x * sc[ci + 0] + sh[ci + 0], 0.0f);
            val.y = fmaxf(val.y * sc[ci + 1] + sh[ci + 1], 0.0f);
            val.z = fmaxf(val.z * sc[ci + 2] + sh[ci + 2], 0.0f);
            val.w = fmaxf(val.w * sc[ci + 3] + sh[ci + 3], 0.0f);
        }
        A_s[ci + 0][r] = val.x;
        A_s[ci + 1][r] = val.y;
        A_s[ci + 2][r] = val.z;
        A_s[ci + 3][r] = val.w;
    }
    __syncthreads();
    int c = t % CT;
    int r0 = (t / CT) * RPT;
    float acc[RPT][J];
    #pragma unroll
    for (int r = 0; r < RPT; r++)
        #pragma unroll
        for (int j = 0; j < J; j++) acc[r][j] = 0.0f;
    #pragma unroll 4
    for (int ci = 0; ci < Cin; ci++) {
        float4 a4[RPT / 4];
        #pragma unroll
        for (int k = 0; k < RPT / 4; k++)
            a4[k] = *(const float4*)&A_s[ci][r0 + 4 * k];
        float w[J];
        #pragma unroll
        for (int j = 0; j < J; j++) w[j] = W_s[ci * Cout + c + CT * j];
        #pragma unroll
        for (int k = 0; k < RPT / 4; k++) {
            #pragma unroll
            for (int j = 0; j < J; j++) {
                acc[4 * k + 0][j] += a4[k].x * w[j];
                acc[4 * k + 1][j] += a4[k].y * w[j];
                acc[4 * k + 2][j] += a4[k].z * w[j];
                acc[4 * k + 3][j] += a4[k].w * w[j];
            }
        }
    }
    float* ob = outp + (size_t)b * NPTS * Cout;
    #pragma unroll
    for (int r = 0; r < RPT; r++) {
        if (r0 + r < nActive) {
            int vout = (int)(pr_s[r0 + r] >> 16);
            #pragma unroll
            for (int j = 0; j < J; j++)
                atomicAdd(&ob[(size_t)vout * Cout + c + CT * j], acc[r][j]);
        }
    }
}

// ---------- BN stats: per-channel sum and sumsq over valid voxels ----------
template <int C>
__global__ void bn_stats(const float* __restrict__ h, const int* __restrict__ nvox,
                         float* __restrict__ sums) {
    constexpr int RPB = 256 / C;
    int b = blockIdx.y;
    int nv = nvox[b];
    int tid = threadIdx.x;
    int c = tid % C;
    int r = tid / C;
    float s0 = 0.0f, s1 = 0.0f;
    for (int v = blockIdx.x * RPB + r; v < nv; v += gridDim.x * RPB) {
        float x = h[((size_t)b * NPTS + v) * C + c];
        s0 += x;
        s1 += x * x;
    }
    __shared__ float l0[256], l1[256];
    l0[tid] = s0; l1[tid] = s1;
    __syncthreads();
    for (int s = 128; s >= C; s >>= 1) {
        if (tid < s) { l0[tid] += l0[tid + s]; l1[tid] += l1[tid + s]; }
        __syncthreads();
    }
    if (tid < C) {
        atomicAdd(&sums[c], l0[tid]);
        atomicAdd(&sums[C + c], l1[tid]);
    }
}

template <int C>
__global__ void bn_finalize(const float* __restrict__ sums, const int* __restrict__ nvox,
                            const float* __restrict__ g, const float* __restrict__ be,
                            float* __restrict__ scale, float* __restrict__ shift) {
    int c = threadIdx.x;
    if (c >= C) return;
    float n = 0.0f;
    for (int b = 0; b < NBATCH; b++) n += (float)nvox[b];
    n = fmaxf(n, 1.0f);
    float mean = sums[c] / n;
    float var = sums[C + c] / n - mean * mean;
    float a = g[c] * rsqrtf(var + 1e-5f);
    scale[c] = a;
    shift[c] = be[c] - mean * a;
}

// ---------- fused BN3 + ReLU + gather to points + mask ----------
__global__ void out_gather(const float* __restrict__ h3, const int* __restrict__ inv,
                           const float* __restrict__ mask, const float* __restrict__ sc,
                           const float* __restrict__ sh, float* __restrict__ out) {
    int b = blockIdx.y;
    size_t i = (size_t)blockIdx.x * blockDim.x + threadIdx.x; // over NPTS*128
    int p = (int)(i >> 7);
    int c = (int)(i & 127);
    size_t gi = (size_t)b * NPTS + p;
    int v = inv[gi];
    float m = mask[gi];
    float x = h3[((size_t)b * NPTS + v) * 128 + c];
    x = fmaxf(x * sc[c] + sh[c], 0.0f);
    out[gi * 128 + c] = x * m;
}

extern "C" void kernel_launch(void* const* d_in, const int* in_sizes, int n_in,
                              void* d_out, int out_size, void* d_ws, size_t ws_size,
                              hipStream_t stream) {
    const float* xyz  = (const float*)d_in[0];
    const float* feat = (const float*)d_in[1];
    const float* mask = (const float*)d_in[2];
    const float* W1 = (const float*)d_in[3];
    const float* b1 = (const float*)d_in[4];
    const float* g1 = (const float*)d_in[5];
    const float* be1 = (const float*)d_in[6];
    const float* W2 = (const float*)d_in[7];
    const float* b2 = (const float*)d_in[8];
    const float* g2 = (const float*)d_in[9];
    const float* be2 = (const float*)d_in[10];
    const float* W3 = (const float*)d_in[11];
    const float* b3 = (const float*)d_in[12];
    const float* g3 = (const float*)d_in[13];
    const float* be3 = (const float*)d_in[14];
    float* out = (float*)d_out;

    char* ws = (char*)d_ws;
    size_t off = 0;
    auto alloc = [&](size_t bytes) {
        void* p = ws + off;
        off += (bytes + 255) & ~(size_t)255;
        return p;
    };
    int*      hashk   = (int*)alloc((size_t)NBATCH * TSIZE * 4);
    int*      hashv   = (int*)alloc((size_t)NBATCH * TSIZE * 4);
    int*      nvox    = (int*)alloc(NBATCH * 4);
    int*      origin  = (int*)alloc(16);
    int*      pcode   = (int*)alloc((size_t)NBATCH * NPTS * 4);
    int*      voxcode = (int*)alloc((size_t)NBATCH * NPTS * 4);
    int*      inv     = (int*)alloc((size_t)NBATCH * NPTS * 4);
    float*    cnt     = (float*)alloc((size_t)NBATCH * NPTS * 4);
    unsigned* pairs   = (unsigned*)alloc((size_t)NBATCH * 27 * CAP * 4);
    int*      paircnt = (int*)alloc(NBATCH * 27 * 4);
    float*    bnsums  = (float*)alloc(256 * 4);
    float*    bnscale = (float*)alloc(128 * 4);
    float*    bnshift = (float*)alloc(128 * 4);
    float*    A       = (float*)alloc((size_t)NBATCH * NPTS * 64 * 4);  // vfeat(16) then h2(64)
    float*    Bb      = (float*)alloc((size_t)NBATCH * NPTS * 128 * 4); // h1(32) then h3(128)

    // ---- zero / sentinel inits (ws is poisoned each call) ----
    hipMemsetAsync(hashk, 0xFF, (size_t)NBATCH * TSIZE * 4, stream); // keys = -1
    hipMemsetAsync(nvox, 0, NBATCH * 4, stream);
    hipMemsetAsync(cnt, 0, (size_t)NBATCH * NPTS * 4, stream);
    hipMemsetAsync(A, 0, (size_t)NBATCH * NPTS * 16 * 4, stream);    // fsum region
    hipMemsetAsync(paircnt, 0, NBATCH * 27 * 4, stream);
    init_origin<<<1, 64, 0, stream>>>(origin);

    // ---- voxelization ----
    minred<<<512, 256, 0, stream>>>(xyz, origin);
    build_codes<<<dim3(NPTS / 256, NBATCH), 256, 0, stream>>>(xyz, origin, pcode, hashk);
    assign_ids<<<dim3(TSIZE / 256, NBATCH), 256, 0, stream>>>(hashk, hashv, nvox, voxcode);
    point_pass<<<dim3(NPTS / 256, NBATCH), 256, 0, stream>>>(pcode, hashk, hashv, feat, mask,
                                                             inv, cnt, A);
    vfeat_div<<<dim3(NPTS * 16 / 256, NBATCH), 256, 0, stream>>>(A, cnt, nvox);

    // ---- rulebook (shared by all 3 layers) ----
    build_pairs<<<dim3(NPTS / 4, NBATCH), 256, 0, stream>>>(hashk, hashv, voxcode, nvox,
                                                            pairs, paircnt);

    dim3 cgrid(NPTS / 64, NBATCH);
    dim3 ogrid(CAP / PPB, NBATCH * 27);

    // ---- layer 1: 16 -> 32 (no input transform) ----
    conv_center<16, 32, false><<<cgrid, 256, 0, stream>>>(A, Bb, W1 + 13 * 16 * 32, b1,
                                                          nullptr, nullptr, nvox);
    conv_off<16, 32, false><<<ogrid, 256, 0, stream>>>(A, Bb, W1, nullptr, nullptr,
                                                       pairs, paircnt);
    hipMemsetAsync(bnsums, 0, 256 * 4, stream);
    bn_stats<32><<<dim3(64, NBATCH), 256, 0, stream>>>(Bb, nvox, bnsums);
    bn_finalize<32><<<1, 128, 0, stream>>>(bnsums, nvox, g1, be1, bnscale, bnshift);

    // ---- layer 2: 32 -> 64 (fused BN1+ReLU on gather) ----
    conv_center<32, 64, true><<<cgrid, 256, 0, stream>>>(Bb, A, W2 + 13 * 32 * 64, b2,
                                                         bnscale, bnshift, nvox);
    conv_off<32, 64, true><<<ogrid, 256, 0, stream>>>(Bb, A, W2, bnscale, bnshift,
                                                      pairs, paircnt);
    hipMemsetAsync(bnsums, 0, 256 * 4, stream);
    bn_stats<64><<<dim3(64, NBATCH), 256, 0, stream>>>(A, nvox, bnsums);
    bn_finalize<64><<<1, 128, 0, stream>>>(bnsums, nvox, g2, be2, bnscale, bnshift);

    // ---- layer 3: 64 -> 128 (fused BN2+ReLU on gather) ----
    conv_center<64, 128, true><<<cgrid, 256, 0, stream>>>(A, Bb, W3 + 13 * 64 * 128, b3,
                                                          bnscale, bnshift, nvox);
    conv_off<64, 128, true><<<ogrid, 256, 0, stream>>>(A, Bb, W3, bnscale, bnshift,
                                                       pairs, paircnt);
    hipMemsetAsync(bnsums, 0, 256 * 4, stream);
    bn_stats<128><<<dim3(64, NBATCH), 256, 0, stream>>>(Bb, nvox, bnsums);
    bn_finalize<128><<<1, 128, 0, stream>>>(bnsums, nvox, g3, be3, bnscale, bnshift);

    // ---- fused BN3 + ReLU + gather + mask ----
    out_gather<<<dim3(NPTS * 128 / 256, NBATCH), 256, 0, stream>>>(Bb, inv, mask, bnscale,
                                                                   bnshift, out);
}

// Round 3
// 3261.793 us; speedup vs baseline: 1.1803x; 1.1370x over previous
//
#include <hip/hip_runtime.h>

#define NPTS   65536
#define NBATCH 8
#define TSIZE  131072
#define TM1    (TSIZE - 1)
#define CAP    8192     // pairs per (b,ko) bucket
#define PPB    64       // pairs per conv_off block

__device__ __forceinline__ unsigned hashf(int code) {
    unsigned u = (unsigned)code * 2654435761u;
    return (u >> 13) & TM1;
}

// ---------- init origin bits to +inf ----------
__global__ void init_origin(int* ob) {
    if (threadIdx.x < 3) ob[threadIdx.x] = 0x7F800000; // +inf
}

// ---------- global per-component min of xyz ----------
__global__ void minred(const float* __restrict__ xyz, int* __restrict__ ob) {
    int tid = threadIdx.x;
    float mx = INFINITY, my = INFINITY, mz = INFINITY;
    size_t total = (size_t)NBATCH * NPTS;
    for (size_t i = (size_t)blockIdx.x * blockDim.x + tid; i < total;
         i += (size_t)gridDim.x * blockDim.x) {
        mx = fminf(mx, xyz[i * 3 + 0]);
        my = fminf(my, xyz[i * 3 + 1]);
        mz = fminf(mz, xyz[i * 3 + 2]);
    }
    __shared__ float sx[256], sy[256], sz[256];
    sx[tid] = mx; sy[tid] = my; sz[tid] = mz;
    __syncthreads();
    for (int s = 128; s > 0; s >>= 1) {
        if (tid < s) {
            sx[tid] = fminf(sx[tid], sx[tid + s]);
            sy[tid] = fminf(sy[tid], sy[tid + s]);
            sz[tid] = fminf(sz[tid], sz[tid + s]);
        }
        __syncthreads();
    }
    if (tid == 0) {
        // coords >= 0 so signed-int compare of float bits preserves order
        atomicMin(&ob[0], __float_as_int(sx[0]));
        atomicMin(&ob[1], __float_as_int(sy[0]));
        atomicMin(&ob[2], __float_as_int(sz[0]));
    }
}

// ---------- voxel codes per point + hash insert ----------
// coords < 128 guaranteed (span 51.2 / 0.4); packed code x | y<<7 | z<<14.
// Any injective code yields the reference's voxel partition; neighbor semantics
// preserved via per-component bounds checks in build_pairs.
__global__ void build_codes(const float* __restrict__ xyz, const int* __restrict__ ob,
                            int* __restrict__ pcode, int* __restrict__ hashk) {
    int b = blockIdx.y;
    int p = blockIdx.x * blockDim.x + threadIdx.x;
    size_t gi = (size_t)b * NPTS + p;
    float ox = __int_as_float(ob[0]);
    float oy = __int_as_float(ob[1]);
    float oz = __int_as_float(ob[2]);
    float x = xyz[gi * 3 + 0], y = xyz[gi * 3 + 1], z = xyz[gi * 3 + 2];
    int vx = (int)((x - ox) / 0.4f); if (vx < 0) vx = 0;
    int vy = (int)((y - oy) / 0.4f); if (vy < 0) vy = 0;
    int vz = (int)((z - oz) / 0.4f); if (vz < 0) vz = 0;
    int code = vx | (vy << 7) | (vz << 14);
    pcode[gi] = code;
    int* hk = hashk + (size_t)b * TSIZE;
    unsigned s = hashf(code);
    while (true) {
        int prev = atomicCAS(&hk[s], -1, code);
        if (prev == -1 || prev == code) break;
        s = (s + 1) & TM1;
    }
}

// ---------- assign voxel ids to occupied hash slots ----------
__global__ void assign_ids(const int* __restrict__ hashk, int* __restrict__ hashv,
                           int* __restrict__ nvox, int* __restrict__ voxcode) {
    int b = blockIdx.y;
    int s = blockIdx.x * blockDim.x + threadIdx.x;
    int k = hashk[(size_t)b * TSIZE + s];
    if (k != -1) {
        int id = atomicAdd(&nvox[b], 1);
        hashv[(size_t)b * TSIZE + s] = id;
        voxcode[(size_t)b * NPTS + id] = k;
    }
}

// ---------- per-point: record inv, accumulate masked feature sums ----------
__global__ void point_pass(const int* __restrict__ pcode, const int* __restrict__ hashk,
                           const int* __restrict__ hashv, const float* __restrict__ feat,
                           const float* __restrict__ mask, int* __restrict__ inv,
                           float* __restrict__ cnt, float* __restrict__ fsum) {
    int b = blockIdx.y;
    int p = blockIdx.x * blockDim.x + threadIdx.x;
    size_t gi = (size_t)b * NPTS + p;
    int code = pcode[gi];
    const int* hk = hashk + (size_t)b * TSIZE;
    unsigned s = hashf(code);
    while (hk[s] != code) s = (s + 1) & TM1;
    int v = hashv[(size_t)b * TSIZE + s];
    inv[gi] = v;
    float m = mask[gi];
    atomicAdd(&cnt[(size_t)b * NPTS + v], m);
    const float* f = feat + gi * 16;
    float* fs = fsum + ((size_t)b * NPTS + v) * 16;
    #pragma unroll
    for (int c = 0; c < 16; c++) atomicAdd(&fs[c], f[c] * m);
}

// ---------- vfeat = fsum / max(cnt,1) ----------
__global__ void vfeat_div(float* __restrict__ fsum, const float* __restrict__ cnt,
                          const int* __restrict__ nvox) {
    int b = blockIdx.y;
    int i = blockIdx.x * blockDim.x + threadIdx.x; // over NPTS*16
    int v = i >> 4;
    if (v >= nvox[b]) return;
    float cn = fmaxf(cnt[(size_t)b * NPTS + v], 1.0f);
    fsum[(size_t)b * NPTS * 16 + i] /= cn;
}

// ---------- build off-center rulebook ----------
// One thread per (voxel, dir) with dir in [0,13): probe the +delta neighbor once;
// on hit emit BOTH (v -> nb, ko=dir) and (nb -> v, ko=26-dir). Packed-code
// bounds checks reproduce the reference's in-bounds test (real coords <= 127,
// so a component hitting 128 can never match an existing voxel).
__global__ void build_pairs(const int* __restrict__ hashk, const int* __restrict__ hashv,
                            const int* __restrict__ voxcode, const int* __restrict__ nvox,
                            unsigned* __restrict__ pairs, int* __restrict__ paircnt) {
    int b = blockIdx.y;
    int i = blockIdx.x * blockDim.x + threadIdx.x; // over NPTS*13
    int v = i / 13;
    int d = i - v * 13;
    if (v >= nvox[b]) return;
    int code = voxcode[(size_t)b * NPTS + v];
    int d9 = d / 9;
    int r9 = d - d9 * 9;
    int r3 = r9 / 3;
    int dz = d9 - 1, dy = r3 - 1, dx = (r9 - r3 * 3) - 1;
    int x = code & 127, y = (code >> 7) & 127, z = code >> 14;
    int nx = x + dx, ny = y + dy, nz = z + dz;
    if ((unsigned)nx > 127u || (unsigned)ny > 127u || (unsigned)nz > 127u) return;
    int ncode = nx | (ny << 7) | (nz << 14);
    const int* hk = hashk + (size_t)b * TSIZE;
    unsigned s = hashf(ncode);
    int nb = -1;
    while (true) {
        int k = hk[s];
        if (k == ncode) { nb = hashv[(size_t)b * TSIZE + s]; break; }
        if (k == -1) break;
        s = (s + 1) & TM1;
    }
    if (nb < 0) return;
    int bucket = b * 27 + d;
    int slot = atomicAdd(&paircnt[bucket], 1);
    if (slot < CAP)
        pairs[(size_t)bucket * CAP + slot] = ((unsigned)v << 16) | (unsigned)nb;
    int bucket2 = b * 27 + (26 - d);
    int slot2 = atomicAdd(&paircnt[bucket2], 1);
    if (slot2 < CAP)
        pairs[(size_t)bucket2 * CAP + slot2] = ((unsigned)nb << 16) | (unsigned)v;
}

// ---------- dense center GEMM: out = xform(in) @ W13 + bias over valid rows ----------
template <int Cin, int Cout, bool XFORM>
__global__ __launch_bounds__(256) void conv_center(
    const float* __restrict__ in, float* __restrict__ outp,
    const float* __restrict__ W13, const float* __restrict__ bias,
    const float* __restrict__ sc, const float* __restrict__ sh,
    const int* __restrict__ nvox) {
    constexpr int BR  = 64;
    constexpr int CT  = (Cout < 64) ? Cout : 64;   // col threads
    constexpr int RG  = 256 / CT;                  // row groups
    constexpr int RPT = BR / RG;                   // rows per thread
    constexpr int J   = Cout / CT;                 // cols per thread
    int b = blockIdx.y;
    int nv = nvox[b];
    int v0 = blockIdx.x * BR;
    if (v0 >= nv) return;
    __shared__ __align__(16) float A_s[Cin][BR + 4];
    __shared__ __align__(16) float W_s[Cin * Cout];
    int t = threadIdx.x;
    for (int i4 = t; i4 < Cin * Cout / 4; i4 += 256)
        ((float4*)W_s)[i4] = ((const float4*)W13)[i4];
    const float* inb = in + (size_t)b * NPTS * Cin;
    for (int i4 = t; i4 < BR * Cin / 4; i4 += 256) {
        int lin = i4 * 4;
        int r = lin / Cin, ci = lin % Cin;
        float4 val = *(const float4*)&inb[(size_t)(v0 + r) * Cin + ci];
        if (XFORM) {
            val.x = fmaxf(val.x * sc[ci + 0] + sh[ci + 0], 0.0f);
            val.y = fmaxf(val.y * sc[ci + 1] + sh[ci + 1], 0.0f);
            val.z = fmaxf(val.z * sc[ci + 2] + sh[ci + 2], 0.0f);
            val.w = fmaxf(val.w * sc[ci + 3] + sh[ci + 3], 0.0f);
        }
        A_s[ci + 0][r] = val.x;
        A_s[ci + 1][r] = val.y;
        A_s[ci + 2][r] = val.z;
        A_s[ci + 3][r] = val.w;
    }
    __syncthreads();
    int c = t % CT;
    int r0 = (t / CT) * RPT;
    float acc[RPT][J];
    #pragma unroll
    for (int r = 0; r < RPT; r++)
        #pragma unroll
        for (int j = 0; j < J; j++) acc[r][j] = 0.0f;
    #pragma unroll 4
    for (int ci = 0; ci < Cin; ci++) {
        float4 a4[RPT / 4];
        #pragma unroll
        for (int k = 0; k < RPT / 4; k++)
            a4[k] = *(const float4*)&A_s[ci][r0 + 4 * k];
        float w[J];
        #pragma unroll
        for (int j = 0; j < J; j++) w[j] = W_s[ci * Cout + c + CT * j];
        #pragma unroll
        for (int k = 0; k < RPT / 4; k++) {
            #pragma unroll
            for (int j = 0; j < J; j++) {
                acc[4 * k + 0][j] += a4[k].x * w[j];
                acc[4 * k + 1][j] += a4[k].y * w[j];
                acc[4 * k + 2][j] += a4[k].z * w[j];
                acc[4 * k + 3][j] += a4[k].w * w[j];
            }
        }
    }
    float* ob = outp + (size_t)b * NPTS * Cout;
    #pragma unroll
    for (int r = 0; r < RPT; r++) {
        int row = v0 + r0 + r;
        if (row < nv) {
            #pragma unroll
            for (int j = 0; j < J; j++)
                ob[(size_t)row * Cout + c + CT * j] = acc[r][j] + bias[c + CT * j];
        }
    }
}

// ---------- off-center: gather pair-rows, GEMM with W[ko] in LDS, scatter-add ----------
template <int Cin, int Cout, bool XFORM>
__global__ __launch_bounds__(256) void conv_off(
    const float* __restrict__ in, float* __restrict__ outp,
    const float* __restrict__ W, const float* __restrict__ sc,
    const float* __restrict__ sh, const unsigned* __restrict__ pairs,
    const int* __restrict__ paircnt) {
    constexpr int BR  = PPB;
    constexpr int CT  = (Cout < 64) ? Cout : 64;
    constexpr int RG  = 256 / CT;
    constexpr int RPT = BR / RG;
    constexpr int J   = Cout / CT;
    int bk = blockIdx.y;            // b*27 + ko
    int ko = bk % 27;
    int b  = bk / 27;
    int cnt = paircnt[bk];
    if (cnt > CAP) cnt = CAP;
    int start = blockIdx.x * BR;
    if (start >= cnt) return;
    int nActive = cnt - start; if (nActive > BR) nActive = BR;
    __shared__ __align__(16) float A_s[Cin][BR + 4];
    __shared__ __align__(16) float W_s[Cin * Cout];
    __shared__ unsigned pr_s[BR];
    int t = threadIdx.x;
    const float* Wk = W + (size_t)ko * Cin * Cout;
    for (int i4 = t; i4 < Cin * Cout / 4; i4 += 256)
        ((float4*)W_s)[i4] = ((const float4*)Wk)[i4];
    const unsigned* pb = pairs + (size_t)bk * CAP + start;
    if (t < BR) pr_s[t] = pb[t];
    __syncthreads();
    const float* inb = in + (size_t)b * NPTS * Cin;
    for (int i4 = t; i4 < BR * Cin / 4; i4 += 256) {
        int lin = i4 * 4;
        int r = lin / Cin, ci = lin % Cin;
        int vin = (int)(pr_s[r] & 0xffffu);
        float4 val = *(const float4*)&inb[(size_t)vin * Cin + ci];
        if (XFORM) {
            val.x = fmaxf(val.x * sc[ci + 0] + sh[ci + 0], 0.0f);
            val.y = fmaxf(val.y * sc[ci + 1] + sh[ci + 1], 0.0f);
            val.z = fmaxf(val.z * sc[ci + 2] + sh[ci + 2], 0.0f);
            val.w = fmaxf(val.w * sc[ci + 3] + sh[ci + 3], 0.0f);
        }
        A_s[ci + 0][r] = val.x;
        A_s[ci + 1][r] = val.y;
        A_s[ci + 2][r] = val.z;
        A_s[ci + 3][r] = val.w;
    }
    __syncthreads();
    int c = t % CT;
    int r0 = (t / CT) * RPT;
    float acc[RPT][J];
    #pragma unroll
    for (int r = 0; r < RPT; r++)
        #pragma unroll
        for (int j = 0; j < J; j++) acc[r][j] = 0.0f;
    #pragma unroll 4
    for (int ci = 0; ci < Cin; ci++) {
        float4 a4[RPT / 4];
        #pragma unroll
        for (int k = 0; k < RPT / 4; k++)
            a4[k] = *(const float4*)&A_s[ci][r0 + 4 * k];
        float w[J];
        #pragma unroll
        for (int j = 0; j < J; j++) w[j] = W_s[ci * Cout + c + CT * j];
        #pragma unroll
        for (int k = 0; k < RPT / 4; k++) {
            #pragma unroll
            for (int j = 0; j < J; j++) {
                acc[4 * k + 0][j] += a4[k].x * w[j];
                acc[4 * k + 1][j] += a4[k].y * w[j];
                acc[4 * k + 2][j] += a4[k].z * w[j];
                acc[4 * k + 3][j] += a4[k].w * w[j];
            }
        }
    }
    float* ob = outp + (size_t)b * NPTS * Cout;
    #pragma unroll
    for (int r = 0; r < RPT; r++) {
        if (r0 + r < nActive) {
            int vout = (int)(pr_s[r0 + r] >> 16);
            #pragma unroll
            for (int j = 0; j < J; j++)
                atomicAdd(&ob[(size_t)vout * Cout + c + CT * j], acc[r][j]);
        }
    }
}

// ---------- BN stats: per-channel sum and sumsq over valid voxels ----------
template <int C>
__global__ void bn_stats(const float* __restrict__ h, const int* __restrict__ nvox,
                         float* __restrict__ sums) {
    constexpr int RPB = 256 / C;
    int b = blockIdx.y;
    int nv = nvox[b];
    int tid = threadIdx.x;
    int c = tid % C;
    int r = tid / C;
    float s0 = 0.0f, s1 = 0.0f;
    for (int v = blockIdx.x * RPB + r; v < nv; v += gridDim.x * RPB) {
        float x = h[((size_t)b * NPTS + v) * C + c];
        s0 += x;
        s1 += x * x;
    }
    __shared__ float l0[256], l1[256];
    l0[tid] = s0; l1[tid] = s1;
    __syncthreads();
    for (int s = 128; s >= C; s >>= 1) {
        if (tid < s) { l0[tid] += l0[tid + s]; l1[tid] += l1[tid + s]; }
        __syncthreads();
    }
    if (tid < C) {
        atomicAdd(&sums[c], l0[tid]);
        atomicAdd(&sums[C + c], l1[tid]);
    }
}

template <int C>
__global__ void bn_finalize(const float* __restrict__ sums, const int* __restrict__ nvox,
                            const float* __restrict__ g, const float* __restrict__ be,
                            float* __restrict__ scale, float* __restrict__ shift) {
    int c = threadIdx.x;
    if (c >= C) return;
    float n = 0.0f;
    for (int b = 0; b < NBATCH; b++) n += (float)nvox[b];
    n = fmaxf(n, 1.0f);
    float mean = sums[c] / n;
    float var = sums[C + c] / n - mean * mean;
    float a = g[c] * rsqrtf(var + 1e-5f);
    scale[c] = a;
    shift[c] = be[c] - mean * a;
}

// ---------- fused BN3 + ReLU + gather to points + mask ----------
__global__ void out_gather(const float* __restrict__ h3, const int* __restrict__ inv,
                           const float* __restrict__ mask, const float* __restrict__ sc,
                           const float* __restrict__ sh, float* __restrict__ out) {
    int b = blockIdx.y;
    size_t i = (size_t)blockIdx.x * blockDim.x + threadIdx.x; // over NPTS*128
    int p = (int)(i >> 7);
    int c = (int)(i & 127);
    size_t gi = (size_t)b * NPTS + p;
    int v = inv[gi];
    float m = mask[gi];
    float x = h3[((size_t)b * NPTS + v) * 128 + c];
    x = fmaxf(x * sc[c] + sh[c], 0.0f);
    out[gi * 128 + c] = x * m;
}

extern "C" void kernel_launch(void* const* d_in, const int* in_sizes, int n_in,
                              void* d_out, int out_size, void* d_ws, size_t ws_size,
                              hipStream_t stream) {
    const float* xyz  = (const float*)d_in[0];
    const float* feat = (const float*)d_in[1];
    const float* mask = (const float*)d_in[2];
    const float* W1 = (const float*)d_in[3];
    const float* b1 = (const float*)d_in[4];
    const float* g1 = (const float*)d_in[5];
    const float* be1 = (const float*)d_in[6];
    const float* W2 = (const float*)d_in[7];
    const float* b2 = (const float*)d_in[8];
    const float* g2 = (const float*)d_in[9];
    const float* be2 = (const float*)d_in[10];
    const float* W3 = (const float*)d_in[11];
    const float* b3 = (const float*)d_in[12];
    const float* g3 = (const float*)d_in[13];
    const float* be3 = (const float*)d_in[14];
    float* out = (float*)d_out;

    char* ws = (char*)d_ws;
    size_t off = 0;
    auto alloc = [&](size_t bytes) {
        void* p = ws + off;
        off += (bytes + 255) & ~(size_t)255;
        return p;
    };
    int*      hashk   = (int*)alloc((size_t)NBATCH * TSIZE * 4);
    int*      hashv   = (int*)alloc((size_t)NBATCH * TSIZE * 4);
    int*      nvox    = (int*)alloc(NBATCH * 4);
    int*      origin  = (int*)alloc(16);
    int*      pcode   = (int*)alloc((size_t)NBATCH * NPTS * 4);
    int*      voxcode = (int*)alloc((size_t)NBATCH * NPTS * 4);
    int*      inv     = (int*)alloc((size_t)NBATCH * NPTS * 4);
    float*    cnt     = (float*)alloc((size_t)NBATCH * NPTS * 4);
    unsigned* pairs   = (unsigned*)alloc((size_t)NBATCH * 27 * CAP * 4);
    int*      paircnt = (int*)alloc(NBATCH * 27 * 4);
    float*    bnsums  = (float*)alloc(256 * 4);
    float*    bnscale = (float*)alloc(128 * 4);
    float*    bnshift = (float*)alloc(128 * 4);
    float*    A       = (float*)alloc((size_t)NBATCH * NPTS * 64 * 4);  // vfeat(16) then h2(64)
    float*    Bb      = (float*)alloc((size_t)NBATCH * NPTS * 128 * 4); // h1(32) then h3(128)

    // ---- zero / sentinel inits (ws is poisoned each call) ----
    hipMemsetAsync(hashk, 0xFF, (size_t)NBATCH * TSIZE * 4, stream); // keys = -1
    hipMemsetAsync(nvox, 0, NBATCH * 4, stream);
    hipMemsetAsync(cnt, 0, (size_t)NBATCH * NPTS * 4, stream);
    hipMemsetAsync(A, 0, (size_t)NBATCH * NPTS * 16 * 4, stream);    // fsum region
    hipMemsetAsync(paircnt, 0, NBATCH * 27 * 4, stream);
    init_origin<<<1, 64, 0, stream>>>(origin);

    // ---- voxelization ----
    minred<<<512, 256, 0, stream>>>(xyz, origin);
    build_codes<<<dim3(NPTS / 256, NBATCH), 256, 0, stream>>>(xyz, origin, pcode, hashk);
    assign_ids<<<dim3(TSIZE / 256, NBATCH), 256, 0, stream>>>(hashk, hashv, nvox, voxcode);
    point_pass<<<dim3(NPTS / 256, NBATCH), 256, 0, stream>>>(pcode, hashk, hashv, feat, mask,
                                                             inv, cnt, A);
    vfeat_div<<<dim3(NPTS * 16 / 256, NBATCH), 256, 0, stream>>>(A, cnt, nvox);

    // ---- rulebook (shared by all 3 layers): thread per (voxel, dir<13) ----
    build_pairs<<<dim3(NPTS * 13 / 256, NBATCH), 256, 0, stream>>>(hashk, hashv, voxcode,
                                                                   nvox, pairs, paircnt);

    dim3 cgrid(NPTS / 64, NBATCH);
    dim3 ogrid(CAP / PPB, NBATCH * 27);

    // ---- layer 1: 16 -> 32 (no input transform) ----
    conv_center<16, 32, false><<<cgrid, 256, 0, stream>>>(A, Bb, W1 + 13 * 16 * 32, b1,
                                                          nullptr, nullptr, nvox);
    conv_off<16, 32, false><<<ogrid, 256, 0, stream>>>(A, Bb, W1, nullptr, nullptr,
                                                       pairs, paircnt);
    hipMemsetAsync(bnsums, 0, 256 * 4, stream);
    bn_stats<32><<<dim3(64, NBATCH), 256, 0, stream>>>(Bb, nvox, bnsums);
    bn_finalize<32><<<1, 128, 0, stream>>>(bnsums, nvox, g1, be1, bnscale, bnshift);

    // ---- layer 2: 32 -> 64 (fused BN1+ReLU on gather) ----
    conv_center<32, 64, true><<<cgrid, 256, 0, stream>>>(Bb, A, W2 + 13 * 32 * 64, b2,
                                                         bnscale, bnshift, nvox);
    conv_off<32, 64, true><<<ogrid, 256, 0, stream>>>(Bb, A, W2, bnscale, bnshift,
                                                      pairs, paircnt);
    hipMemsetAsync(bnsums, 0, 256 * 4, stream);
    bn_stats<64><<<dim3(64, NBATCH), 256, 0, stream>>>(A, nvox, bnsums);
    bn_finalize<64><<<1, 128, 0, stream>>>(bnsums, nvox, g2, be2, bnscale, bnshift);

    // ---- layer 3: 64 -> 128 (fused BN2+ReLU on gather) ----
    conv_center<64, 128, true><<<cgrid, 256, 0, stream>>>(A, Bb, W3 + 13 * 64 * 128, b3,
                                                          bnscale, bnshift, nvox);
    conv_off<64, 128, true><<<ogrid, 256, 0, stream>>>(A, Bb, W3, bnscale, bnshift,
                                                       pairs, paircnt);
    hipMemsetAsync(bnsums, 0, 256 * 4, stream);
    bn_stats<128><<<dim3(64, NBATCH), 256, 0, stream>>>(Bb, nvox, bnsums);
    bn_finalize<128><<<1, 128, 0, stream>>>(bnsums, nvox, g3, be3, bnscale, bnshift);

    // ---- fused BN3 + ReLU + gather + mask ----
    out_gather<<<dim3(NPTS * 128 / 256, NBATCH), 256, 0, stream>>>(Bb, inv, mask, bnscale,
                                                                   bnshift, out);
}